// Round 5
// baseline (44.801 us; speedup 1.0000x reference)
//
#include <hip/hip_runtime.h>

// Problem constants
#define NSPLIT  100
#define MTREE   20
#define MAXLEAF 64
#define EMB     32
#define NTREES  2000
#define BATCH   4096
#define OUTW    (NSPLIT*EMB)            // 3200

#define THREADS 1024
#define NBLK    512                     // = 2 exact dispatch rounds at 1 block/CU
#define IPB     ((BATCH*NSPLIT)/NBLK)   // 800 (batch,split) pairs per block
#define LTREES  16                      // trees staged in LDS
#define LDS_F4  (LTREES*MAXLEAF*8)      // 8192 float4 = 128 KiB
#define LDS_BYTES (LDS_F4*16)
#define TAB_F4  (MTREE*MAXLEAF*8)       // 10240 float4 per split table

// v5: balanced linearized work + dual-pipe gather.
//  - (split,batch) space linearized: block k owns pairs [k*800,(k+1)*800).
//    512 blocks @ 1/CU = exactly 2 clean rounds (v4's 800 blocks = 3.125
//    rounds + full straggler round = 28% tail loss). ~19% of blocks span a
//    split boundary and re-stage once mid-block.
//  - Trees 0..15 gathered from LDS (row-major, conflict-free 128B row per
//    8-lane group); trees 16..19 gathered straight from the L2-resident
//    table (independent pipe, ~15 TB/s chip-wide), issued BEFORE the LDS
//    reads so global latency hides under LDS port work.
__device__ __forceinline__ void stage_dma(const float4* gsrc, void* lbase) {
    __builtin_amdgcn_global_load_lds(
        (const __attribute__((address_space(1))) void*)gsrc,
        (__attribute__((address_space(3))) void*)lbase, 16, 0, 0);
}

__global__ __launch_bounds__(THREADS) void leaf2emb_v5(
    const int* __restrict__ leaves,     // [BATCH, NTREES]
    const float* __restrict__ embed,    // [NSPLIT, MTREE*MAXLEAF, EMB]
    float* __restrict__ out)            // [BATCH, OUTW]
{
    extern __shared__ float4 tab[];     // 8192 float4 = 128 KiB

    // XCD-chunked swizzle: XCD x (assuming round-robin bid->XCD) handles 64
    // contiguous work units (~12.5 consecutive splits) -> staging reads of a
    // split's table stay in one XCD's L2.
    const int bid = blockIdx.x;
    const int wkr = (bid & 7) * (NBLK / 8) + (bid >> 3);

    const int tid  = threadIdx.x;
    const int e4   = tid & 7;           // float4 slice of the 32-wide row
    const int g    = tid >> 3;          // gather group (8 lanes)
    const int w    = tid >> 6;          // wave id
    const int lane = tid & 63;

    int s      = (wkr * IPB) >> 12;     // current split
    int bstart = (wkr * IPB) & 4095;    // first batch in segment
    int remain = IPB;

    while (remain > 0) {
        const int cnt = min(remain, BATCH - bstart);
        const float4* emb4 = (const float4*)embed + (size_t)s * TAB_F4;

        if (remain != IPB) __syncthreads();   // prev segment's gathers done
        // stage trees 0..15 (128 KiB): wave w owns float4 [w*512, w*512+512)
        {
            const float4* gs = emb4 + w * 512 + lane;
            char* lb = (char*)(tab + w * 512);
#pragma unroll
            for (int k = 0; k < 8; ++k)
                stage_dma(gs + k * 64, lb + k * 1024);
        }
        __syncthreads();                      // DMA drained (vmcnt before barrier)

        for (int b = bstart + g; b < bstart + cnt; b += 128) {
            const int* lv = leaves + (size_t)b * NTREES + s * MTREE;
            const int4 L0 = *(const int4*)(lv + 0);
            const int4 L1 = *(const int4*)(lv + 4);
            const int4 L2 = *(const int4*)(lv + 8);
            const int4 L3 = *(const int4*)(lv + 12);
            const int4 L4 = *(const int4*)(lv + 16);

            // trees 16..19 via global (L2-resident) — issue before LDS reads
            const float4* gb = emb4 + LTREES * 512 + e4;
            const float4 q0 = gb[0 * 512 + L4.x * 8];
            const float4 q1 = gb[1 * 512 + L4.y * 8];
            const float4 q2 = gb[2 * 512 + L4.z * 8];
            const float4 q3 = gb[3 * 512 + L4.w * 8];

            float4 acc = {0.f, 0.f, 0.f, 0.f};
#define GT(BC, JJ, LEAF) { float4 v_ = (BC)[((JJ)*64 + (LEAF))*8];      \
            acc.x += v_.x; acc.y += v_.y; acc.z += v_.z; acc.w += v_.w; }
            { const float4* bc = tab + e4;        GT(bc,0,L0.x) GT(bc,1,L0.y) GT(bc,2,L0.z) GT(bc,3,L0.w) }
            { const float4* bc = tab + 2048 + e4; GT(bc,0,L1.x) GT(bc,1,L1.y) GT(bc,2,L1.z) GT(bc,3,L1.w) }
            { const float4* bc = tab + 4096 + e4; GT(bc,0,L2.x) GT(bc,1,L2.y) GT(bc,2,L2.z) GT(bc,3,L2.w) }
            { const float4* bc = tab + 6144 + e4; GT(bc,0,L3.x) GT(bc,1,L3.y) GT(bc,2,L3.z) GT(bc,3,L3.w) }
#undef GT
            acc.x += q0.x + q1.x + q2.x + q3.x;
            acc.y += q0.y + q1.y + q2.y + q3.y;
            acc.z += q0.z + q1.z + q2.z + q3.z;
            acc.w += q0.w + q1.w + q2.w + q3.w;

            // 8 lanes x 16B = contiguous 128B per (b, s)
            *(float4*)(out + (size_t)b * OUTW + s * EMB + e4 * 4) = acc;
        }

        remain -= cnt;
        bstart = 0;
        s += 1;
    }
}

extern "C" void kernel_launch(void* const* d_in, const int* in_sizes, int n_in,
                              void* d_out, int out_size, void* d_ws, size_t ws_size,
                              hipStream_t stream) {
    const int* leaves  = (const int*)d_in[0];
    const float* embed = (const float*)d_in[1];
    float* out         = (float*)d_out;

    (void)hipFuncSetAttribute((const void*)leaf2emb_v5,
                              hipFuncAttributeMaxDynamicSharedMemorySize,
                              LDS_BYTES);

    dim3 grid(NBLK);        // 512
    dim3 block(THREADS);    // 1024
    leaf2emb_v5<<<grid, block, LDS_BYTES, stream>>>(leaves, embed, out);
}